// Round 6
// baseline (188.794 us; speedup 1.0000x reference)
//
#include <hip/hip_runtime.h>

// Problem constants
#define N_TOK 8192
#define N_EXP 8
#define DIM   2048
#define HID   2048

typedef __attribute__((ext_vector_type(8))) short short8;
typedef __attribute__((ext_vector_type(4))) float f32x4;
typedef __attribute__((ext_vector_type(4))) unsigned short ushort4v;

__device__ inline unsigned short f2bf(float f) {
  unsigned int u = __builtin_bit_cast(unsigned int, f);
  unsigned int r = u + 0x7FFFu + ((u >> 16) & 1u);   // round-to-nearest-even
  return (unsigned short)(r >> 16);
}

// ---------------------------------------------------------------------------
// Kernel 1: stable counting sort by expert id + compact job list.
// perm[p] = source row; offs[e..e+1] = segment bounds;
// jobs[0] = n_mjobs; jobs[1+j] = e | (mt<<8)  (256-row M-bands).
// ---------------------------------------------------------------------------
__global__ __launch_bounds__(256) void sort_experts(const int* __restrict__ idx,
                                                    int* __restrict__ perm,
                                                    int* __restrict__ offs,
                                                    int* __restrict__ jobs) {
  __shared__ int cnt[256][8];
  __shared__ int base[8];
  const int t = threadIdx.x;
  int local[8] = {0,0,0,0,0,0,0,0};
  const int r0 = t * 32;
  for (int i = 0; i < 32; ++i) {
    int e = idx[r0 + i] & 7;
    ++local[e];
  }
#pragma unroll
  for (int e = 0; e < 8; ++e) cnt[t][e] = local[e];
  __syncthreads();
  if (t < 8) {
    int s = 0;
    for (int i = 0; i < 256; ++i) { int v = cnt[i][t]; cnt[i][t] = s; s += v; }
    base[t] = s;
  }
  __syncthreads();
  if (t == 0) {
    int s = 0, njm = 0;
    for (int e = 0; e < 8; ++e) {
      int v = base[e];
      offs[e] = s; base[e] = s; s += v;
      int nm = (v + 255) >> 8;
      for (int mt = 0; mt < nm; ++mt) jobs[1 + njm++] = e | (mt << 8);
    }
    offs[8] = s;
    jobs[0] = njm;
  }
  __syncthreads();
  int pos[8];
#pragma unroll
  for (int e = 0; e < 8; ++e) pos[e] = base[e] + cnt[t][e];
  for (int i = 0; i < 32; ++i) {
    int r = r0 + i;
    int e = idx[r] & 7;
    perm[pos[e]++] = r;
  }
}

// ---------------------------------------------------------------------------
// Kernel 2: merged prep. Blocks [0,8192): gather+convert x (sorted bf16).
// Blocks [8192,16384): W[e][d][h] fp32 -> Wt[e][h][d] bf16 (LDS transpose).
// ---------------------------------------------------------------------------
__global__ __launch_bounds__(256) void prep(const float* __restrict__ x,
                                            const int* __restrict__ perm,
                                            unsigned short* __restrict__ xs,
                                            const float* __restrict__ W,
                                            unsigned short* __restrict__ Wt) {
  __shared__ unsigned short tile[64][68];
  const int t = threadIdx.x;
  if (blockIdx.x < 8192) {
    int gid = blockIdx.x * 256 + t;
    int p = gid >> 8;
    int c = gid & 255;
    int src = perm[p];
    const float* sp = x + (size_t)src * DIM + c * 8;
    float4 a = *(const float4*)sp;
    float4 b = *(const float4*)(sp + 4);
    short8 o;
    o[0] = (short)f2bf(a.x); o[1] = (short)f2bf(a.y);
    o[2] = (short)f2bf(a.z); o[3] = (short)f2bf(a.w);
    o[4] = (short)f2bf(b.x); o[5] = (short)f2bf(b.y);
    o[6] = (short)f2bf(b.z); o[7] = (short)f2bf(b.w);
    *(short8*)(xs + (size_t)p * DIM + c * 8) = o;
  } else {
    const int b = blockIdx.x - 8192;
    const int e  = b >> 10;
    const int d0 = ((b >> 5) & 31) * 64;
    const int h0 = (b & 31) * 64;
    const int cr = t & 15;
    const int rr = t >> 4;
    const float* Wp = W + ((size_t)e * DIM + d0) * HID + h0;
#pragma unroll
    for (int i = 0; i < 4; ++i) {
      int d = rr + i * 16;
      float4 v = *(const float4*)(Wp + (size_t)d * HID + cr * 4);
      ushort4v o;
      o[0] = f2bf(v.x); o[1] = f2bf(v.y); o[2] = f2bf(v.z); o[3] = f2bf(v.w);
      *(ushort4v*)&tile[d][cr * 4] = o;
    }
    __syncthreads();
    unsigned short* op = Wt + ((size_t)e * HID + h0) * DIM + d0;
#pragma unroll
    for (int i = 0; i < 4; ++i) {
      int h = rr + i * 16;
      ushort4v o;
      o[0] = tile[cr * 4 + 0][h];
      o[1] = tile[cr * 4 + 1][h];
      o[2] = tile[cr * 4 + 2][h];
      o[3] = tile[cr * 4 + 3][h];
      *(ushort4v*)(op + (size_t)h * DIM + cr * 4) = o;
    }
  }
}

// ---------------------------------------------------------------------------
// Kernel 3: PERSISTENT grouped GEMM. Exactly 256 blocks (1/CU), 8 waves
// (4M x 2N, per-wave 64x64). Each block loops compact jobs: 256(M) x 128(N)
// tiles, job idx = jm*16 + nx (B-panel sharers at stride 16 -> same XCD).
// Inner: BK=64, 3 LDS slots (144 KiB), stage tile T+2, 2 phases/K-tile,
// vmcnt(6) once per tile (R4-verified cadence). Swizzle (R3-verified):
// byte[6:4] ^= row[2:0] on reads, inverse pre-applied to staging sources.
// ---------------------------------------------------------------------------
#define NKT 32           // K-tiles of 64
#define SLOT 24576       // ushorts: A [0,16384) = 256x64, B [16384,24576) = 128x64

#define MM(D,A,B) D = __builtin_amdgcn_mfma_f32_16x16x32_bf16(A, B, D, 0, 0, 0)
#define GLD(SRC, DST) __builtin_amdgcn_global_load_lds( \
    (const __attribute__((address_space(1))) void*)(SRC), \
    (__attribute__((address_space(3))) void*)(DST), 16, 0, 0)
#define BAR() __builtin_amdgcn_s_barrier()
#define PRIO(x) __builtin_amdgcn_s_setprio(x)

__global__ __launch_bounds__(512, 2) void grouped_gemm(
    const unsigned short* __restrict__ xs,
    const unsigned short* __restrict__ Wt,
    const float* __restrict__ bias,
    const int* __restrict__ offs,
    const int* __restrict__ jobs,
    float* __restrict__ out) {
  __shared__ __align__(16) unsigned short sm[3 * SLOT];   // 144 KiB

  const int t    = threadIdx.x;
  const int lane = t & 63;
  const int wid  = t >> 6;
  const int wr   = wid >> 1;   // 0..3  (M quarter: rows wr*64)
  const int wc   = wid & 1;    // 0..1  (N half:    cols wc*64)
  const int l15  = lane & 15;
  const int l4   = lane >> 4;

  // Fragment LDS offsets (ushort units); row stride 64 ush (128B).
  const int cb0  = (l4 * 8) ^ ((l15 & 7) << 3);
  const int cb1  = cb0 ^ 32;
  const int arow = (wr * 64 + l15) * 64;           // + m*1024
  const int brow = 16384 + (wc * 64 + l15) * 64;   // + n*1024

  // Staging geometry: chunk = 8KB (64 rows x 64 k-elems), thread t covers
  // row r0 = t>>3, 16B col (t&7); inverse swizzle pre-applied to k index.
  const int r0  = t >> 3;
  const int keu = ((t & 7) * 8) ^ ((r0 & 7) << 3);
  const int dA = t * 8;

  const int njm   = jobs[0];
  const int total = njm * 16;

#pragma unroll 1
  for (int idx = blockIdx.x; idx < total; idx += 256) {
    const int jm  = jobs[1 + (idx >> 4)];
    const int e   = jm & 255;
    const int mt  = jm >> 8;
    const int nx  = idx & 15;
    const int off = offs[e];
    const int cnt = offs[e + 1] - off;
    const int aBase = off + mt * 256;
    const int n0  = nx * 128;

    // Per-job staging source bases (element offsets at k=0).
    unsigned int pa0, pa1, pa2, pa3, pb0, pb1;
    {
      int p;
      p = aBase + 0 * 64 + r0; if (p > N_TOK - 1) p = N_TOK - 1; pa0 = (unsigned)p * 2048 + keu;
      p = aBase + 1 * 64 + r0; if (p > N_TOK - 1) p = N_TOK - 1; pa1 = (unsigned)p * 2048 + keu;
      p = aBase + 2 * 64 + r0; if (p > N_TOK - 1) p = N_TOK - 1; pa2 = (unsigned)p * 2048 + keu;
      p = aBase + 3 * 64 + r0; if (p > N_TOK - 1) p = N_TOK - 1; pa3 = (unsigned)p * 2048 + keu;
      unsigned int eW = (unsigned)e * (DIM * HID);
      pb0 = eW + (unsigned)(n0 + 0 * 64 + r0) * 2048 + keu;
      pb1 = eW + (unsigned)(n0 + 1 * 64 + r0) * 2048 + keu;
    }

#define ST_HALF1(SBASE, KOFS) do { \
    GLD(xs + pa0 + (KOFS), sm + (SBASE) + 0 * 4096 + dA); \
    GLD(xs + pa1 + (KOFS), sm + (SBASE) + 1 * 4096 + dA); \
    GLD(xs + pa2 + (KOFS), sm + (SBASE) + 2 * 4096 + dA); } while (0)
#define ST_HALF2(SBASE, KOFS) do { \
    GLD(xs + pa3 + (KOFS), sm + (SBASE) + 3 * 4096 + dA); \
    GLD(Wt + pb0 + (KOFS), sm + (SBASE) + 16384 + 0 * 4096 + dA); \
    GLD(Wt + pb1 + (KOFS), sm + (SBASE) + 16384 + 1 * 4096 + dA); } while (0)

    f32x4 acc[4][4] = {};

    // Prologue: tiles 0,1 -> slots 0,1.
    ST_HALF1(0, 0);        ST_HALF2(0, 0);
    ST_HALF1(SLOT, 64);    ST_HALF2(SLOT, 64);
    asm volatile("s_waitcnt vmcnt(6)" ::: "memory");   // tile0 landed
    BAR();

    short8 fa0, fa1, fa2, fa3, fb0, fb1, fb2, fb3;
    int sl = 0;   // slot of tile T
    int s2 = 2;   // slot of tile T+2

#pragma unroll 1
    for (int T = 0; T < NKT; ++T) {
      const unsigned short* SP = sm + sl * SLOT;
      const int sb = s2 * SLOT;
      const int kofs = (T + 2) * 64;
      const bool st = (T < NKT - 2);

      // ---- phase 0: ksub0 ----
      fa0 = *(const short8*)(SP + arow + 0 * 1024 + cb0);
      fa1 = *(const short8*)(SP + arow + 1 * 1024 + cb0);
      fa2 = *(const short8*)(SP + arow + 2 * 1024 + cb0);
      fa3 = *(const short8*)(SP + arow + 3 * 1024 + cb0);
      fb0 = *(const short8*)(SP + brow + 0 * 1024 + cb0);
      fb1 = *(const short8*)(SP + brow + 1 * 1024 + cb0);
      fb2 = *(const short8*)(SP + brow + 2 * 1024 + cb0);
      fb3 = *(const short8*)(SP + brow + 3 * 1024 + cb0);
      if (st) ST_HALF1(sb, kofs);
      BAR(); PRIO(1);
      MM(acc[0][0],fa0,fb0); MM(acc[0][1],fa0,fb1); MM(acc[0][2],fa0,fb2); MM(acc[0][3],fa0,fb3);
      MM(acc[1][0],fa1,fb0); MM(acc[1][1],fa1,fb1); MM(acc[1][2],fa1,fb2); MM(acc[1][3],fa1,fb3);
      MM(acc[2][0],fa2,fb0); MM(acc[2][1],fa2,fb1); MM(acc[2][2],fa2,fb2); MM(acc[2][3],fa2,fb3);
      MM(acc[3][0],fa3,fb0); MM(acc[3][1],fa3,fb1); MM(acc[3][2],fa3,fb2); MM(acc[3][3],fa3,fb3);
      PRIO(0); BAR();

      // ---- phase 1: ksub1 ----
      fa0 = *(const short8*)(SP + arow + 0 * 1024 + cb1);
      fa1 = *(const short8*)(SP + arow + 1 * 1024 + cb1);
      fa2 = *(const short8*)(SP + arow + 2 * 1024 + cb1);
      fa3 = *(const short8*)(SP + arow + 3 * 1024 + cb1);
      fb0 = *(const short8*)(SP + brow + 0 * 1024 + cb1);
      fb1 = *(const short8*)(SP + brow + 1 * 1024 + cb1);
      fb2 = *(const short8*)(SP + brow + 2 * 1024 + cb1);
      fb3 = *(const short8*)(SP + brow + 3 * 1024 + cb1);
      if (st) ST_HALF2(sb, kofs);
      BAR(); PRIO(1);
      MM(acc[0][0],fa0,fb0); MM(acc[0][1],fa0,fb1); MM(acc[0][2],fa0,fb2); MM(acc[0][3],fa0,fb3);
      MM(acc[1][0],fa1,fb0); MM(acc[1][1],fa1,fb1); MM(acc[1][2],fa1,fb2); MM(acc[1][3],fa1,fb3);
      MM(acc[2][0],fa2,fb0); MM(acc[2][1],fa2,fb1); MM(acc[2][2],fa2,fb2); MM(acc[2][3],fa2,fb3);
      MM(acc[3][0],fa3,fb0); MM(acc[3][1],fa3,fb1); MM(acc[3][2],fa3,fb2); MM(acc[3][3],fa3,fb3);
      PRIO(0);
      // Tile T+1 must have landed before next phase reads it.
      if (T < NKT - 2)       { asm volatile("s_waitcnt vmcnt(6)" ::: "memory"); }
      else if (T == NKT - 2) { asm volatile("s_waitcnt vmcnt(0)" ::: "memory"); }
      BAR();

      sl = (sl == 2) ? 0 : sl + 1;
      s2 = (s2 == 2) ? 0 : s2 + 1;
    }

    // Epilogue: bias + relu, masked tail rows.
#pragma unroll
    for (int n = 0; n < 4; ++n) {
      int col = n0 + wc * 64 + n * 16 + l15;
      float bv = bias[e * HID + col];
#pragma unroll
      for (int m = 0; m < 4; ++m) {
#pragma unroll
        for (int q = 0; q < 4; ++q) {
          int r = wr * 64 + m * 16 + l4 * 4 + q;
          if (mt * 256 + r < cnt) {
            float v = acc[m][n][q] + bv;
            out[(size_t)(off + mt * 256 + r) * HID + col] = v > 0.f ? v : 0.f;
          }
        }
      }
    }
  }
#undef ST_HALF1
#undef ST_HALF2
}

// ---------------------------------------------------------------------------
extern "C" void kernel_launch(void* const* d_in, const int* in_sizes, int n_in,
                              void* d_out, int out_size, void* d_ws, size_t ws_size,
                              hipStream_t stream) {
  const float* x   = (const float*)d_in[0];
  const int*   idx = (const int*)d_in[1];
  const float* W   = (const float*)d_in[2];
  const float* b   = (const float*)d_in[3];
  float* out = (float*)d_out;

  char* ws = (char*)d_ws;
  unsigned short* xs = (unsigned short*)ws;                                   // 32 MB
  unsigned short* Wt = (unsigned short*)(ws + (size_t)N_TOK * DIM * 2);       // 64 MB
  int* perm = (int*)(ws + (size_t)N_TOK * DIM * 2 + (size_t)N_EXP * DIM * HID * 2);
  int* offs = perm + N_TOK;
  int* jobs = offs + 16;

  sort_experts<<<1, 256, 0, stream>>>(idx, perm, offs, jobs);
  prep<<<16384, 256, 0, stream>>>(x, perm, xs, W, Wt);
  grouped_gemm<<<256, 512, 0, stream>>>(xs, Wt, b, offs, jobs, out);
}